// Round 5
// baseline (810.735 us; speedup 1.0000x reference)
//
#include <hip/hip_runtime.h>

#define NN 8192      // rows == cols
#define DD 64        // inner dim
#define ROWS 16      // rows per block (one 16-row MFMA band)
#define NT 1024      // threads per block = 16 waves
#define NWAVE 16
#define TPW 32       // 16-col tiles per wave: 8192 / 16 waves / 16 cols
#define NBINS 128
#define LCAP 64
#define WINDOW 12.0f // values below rowmax-12 contribute < 6e-6 to any output

typedef _Float16 half8 __attribute__((ext_vector_type(8)));
typedef _Float16 half2 __attribute__((ext_vector_type(2)));
typedef float    f32x4 __attribute__((ext_vector_type(4)));

__global__ __launch_bounds__(NT, 4) void sag_mfma(
    const float* __restrict__ nv1,
    const float* __restrict__ nv2,
    const int* __restrict__ topkp,
    float* __restrict__ out)
{
    __shared__ int   hist[ROWS][NBINS];
    __shared__ float blist[ROWS][LCAP];
    __shared__ int   bcount[ROWS];
    __shared__ float mpart[NWAVE][ROWS];
    __shared__ float zpart[NWAVE][ROWS];
    __shared__ int   cpart[NWAVE][ROWS];
    __shared__ float m_f[ROWS];
    __shared__ float tsel[ROWS];
    __shared__ float zsum[ROWS];
    __shared__ int   scnt[ROWS];
    __shared__ int   binb[ROWS];
    __shared__ int   needv[ROWS];

    const int tid  = threadIdx.x;
    const int wv   = tid >> 6;          // wave 0..15
    const int ln   = tid & 63;
    const int g    = ln >> 4;           // lane group 0..3 (k-group / row-quad)
    const int cl   = ln & 15;           // col-within-tile, also A-row index
    const int row0 = blockIdx.x * ROWS;
    const int K    = topkp[0];

    // ---- init LDS ----
    for (int i = tid; i < ROWS * NBINS; i += NT) (&hist[0][0])[i] = 0;
    if (tid < ROWS) bcount[tid] = 0;

    // ---- A fragments (whole 16x64 A panel, fp16): af[ks][j] = A[row0+cl][8g+j+32ks]
    half8 af[2];
    {
        const float* pa = nv1 + (size_t)(row0 + cl) * DD + g * 8;
        #pragma unroll
        for (int ks = 0; ks < 2; ++ks)
            #pragma unroll
            for (int j = 0; j < 8; ++j)
                af[ks][j] = (_Float16)pa[ks * 32 + j];
    }
    __syncthreads();

    // ---- GEMM: wave wv owns cols [wv*512, wv*512+512); per tile 16 cols ----
    // C/D layout (m89-verified): lane holds col = cl, rows g*4 + {0,1,2,3} (= acc[0..3])
    // B frag uses the SAME k-bijection as A: B[8g+j+32ks][col]
    const int wbase = wv * (NN / NWAVE);
    const float* pb = nv2 + (size_t)(g * 8) * NN + wbase + cl;

    half2 s01[TPW];  // packed scores, rows g*4+0, g*4+1
    half2 s23[TPW];  // packed scores, rows g*4+2, g*4+3

    #pragma unroll 2
    for (int t = 0; t < TPW; ++t) {
        const int co = t * 16;
        f32x4 acc = {0.f, 0.f, 0.f, 0.f};
        half8 bf;
        #pragma unroll
        for (int j = 0; j < 8; ++j)
            bf[j] = (_Float16)pb[(size_t)j * NN + co];
        acc = __builtin_amdgcn_mfma_f32_16x16x32_f16(af[0], bf, acc, 0, 0, 0);
        #pragma unroll
        for (int j = 0; j < 8; ++j)
            bf[j] = (_Float16)pb[(size_t)(32 + j) * NN + co];
        acc = __builtin_amdgcn_mfma_f32_16x16x32_f16(af[1], bf, acc, 0, 0, 0);
        // relu + pack to fp16 storage
        s01[t].x = (_Float16)fmaxf(acc[0], 0.f);
        s01[t].y = (_Float16)fmaxf(acc[1], 0.f);
        s23[t].x = (_Float16)fmaxf(acc[2], 0.f);
        s23[t].y = (_Float16)fmaxf(acc[3], 0.f);
    }

    // ---- row max over stored (fp16-rounded) values ----
    float mx[4] = {0.f, 0.f, 0.f, 0.f};
    #pragma unroll
    for (int t = 0; t < TPW; ++t) {
        mx[0] = fmaxf(mx[0], (float)s01[t].x);
        mx[1] = fmaxf(mx[1], (float)s01[t].y);
        mx[2] = fmaxf(mx[2], (float)s23[t].x);
        mx[3] = fmaxf(mx[3], (float)s23[t].y);
    }
    #pragma unroll
    for (int off = 1; off <= 8; off <<= 1) {
        #pragma unroll
        for (int i = 0; i < 4; ++i) mx[i] = fmaxf(mx[i], __shfl_xor(mx[i], off));
    }
    if (cl == 0) {
        #pragma unroll
        for (int i = 0; i < 4; ++i) mpart[wv][g * 4 + i] = mx[i];
    }
    __syncthreads();
    if (tid < ROWS) {
        float mm = 0.f;
        for (int w = 0; w < NWAVE; ++w) mm = fmaxf(mm, mpart[w][tid]);
        m_f[tid] = mm;
    }
    __syncthreads();

    // ---- histogram of in-window values ----
    const float invw = (float)NBINS / WINDOW;
    #pragma unroll
    for (int i = 0; i < 4; ++i) {
        const int   row = g * 4 + i;
        const float lbr = fmaxf(m_f[row] - WINDOW, 0.f);
        #pragma unroll
        for (int t = 0; t < TPW; ++t) {
            const float v = (i < 2) ? (float)((i == 0) ? s01[t].x : s01[t].y)
                                    : (float)((i == 2) ? s23[t].x : s23[t].y);
            if (v > lbr) {
                int bi = (int)((v - lbr) * invw);
                bi = bi < NBINS - 1 ? bi : NBINS - 1;
                atomicAdd(&hist[row][bi], 1);
            }
        }
    }
    __syncthreads();

    // ---- scan from top: boundary bin where cumulative reaches K ----
    if (tid < ROWS) {
        int cum = 0, b = -1, nd = 0;
        for (int i = NBINS - 1; i >= 0; --i) {
            const int h = hist[tid][i];
            if (cum + h >= K) { b = i; nd = K - cum; break; }
            cum += h;
        }
        binb[tid]  = b;
        needv[tid] = nd;
        if (b < 0) tsel[tid] = fmaxf(m_f[tid] - WINDOW, 0.f);
    }
    __syncthreads();

    // ---- collect boundary-bin values ----
    #pragma unroll
    for (int i = 0; i < 4; ++i) {
        const int row = g * 4 + i;
        const int b   = binb[row];
        if (b >= 0) {
            const float lbr = fmaxf(m_f[row] - WINDOW, 0.f);
            #pragma unroll
            for (int t = 0; t < TPW; ++t) {
                const float v = (i < 2) ? (float)((i == 0) ? s01[t].x : s01[t].y)
                                        : (float)((i == 2) ? s23[t].x : s23[t].y);
                if (v > lbr) {
                    int bi = (int)((v - lbr) * invw);
                    bi = bi < NBINS - 1 ? bi : NBINS - 1;
                    if (bi == b) {
                        const int p = atomicAdd(&bcount[row], 1);
                        if (p < LCAP) blist[row][p] = v;
                    }
                }
            }
        }
    }
    __syncthreads();

    // ---- exact rank within boundary bin: wave r refines row r ----
    {
        const int r = wv;   // 16 waves == 16 rows
        if (binb[r] >= 0) {
            const int n  = min(bcount[r], LCAP);
            const int nd = needv[r];
            const float v = (ln < n) ? blist[r][ln] : -1.f;
            int rank = 0;
            for (int j = 0; j < LCAP; ++j) {
                const float vj = __shfl(v, j);
                rank += (vj > v) ? 1 : 0;
            }
            float cand = (ln < n && rank < nd) ? v : 3.4e38f;
            #pragma unroll
            for (int off = 32; off; off >>= 1) cand = fminf(cand, __shfl_xor(cand, off));
            if (ln == 0) tsel[r] = __int_as_float(__float_as_int(cand) - 1);
        }
    }
    __syncthreads();

    // ---- Z reduction (deterministic order) ----
    #pragma unroll
    for (int i = 0; i < 4; ++i) {
        const int   row = g * 4 + i;
        const float mr  = m_f[row];
        const float th  = tsel[row];
        float part = 0.f;
        int   cnt  = 0;
        #pragma unroll
        for (int t = 0; t < TPW; ++t) {
            const float v = (i < 2) ? (float)((i == 0) ? s01[t].x : s01[t].y)
                                    : (float)((i == 2) ? s23[t].x : s23[t].y);
            const bool sel = v > th;
            const float e  = __expf(v - mr);
            part += sel ? e : 0.f;
            cnt  += sel ? 1 : 0;
        }
        #pragma unroll
        for (int off = 1; off <= 8; off <<= 1) {
            part += __shfl_xor(part, off);
            cnt  += __shfl_xor(cnt, off);
        }
        if (cl == 0) { zpart[wv][row] = part; cpart[wv][row] = cnt; }
    }
    __syncthreads();
    if (tid < ROWS) {
        float z = 0.f; int c2 = 0;
        for (int w = 0; w < NWAVE; ++w) { z += zpart[w][tid]; c2 += cpart[w][tid]; }
        zsum[tid] = z; scnt[tid] = c2;
    }
    __syncthreads();

    // ---- write: selected -> exp(v-m)/Z, else exp(-m)/Z ----
    #pragma unroll
    for (int i = 0; i < 4; ++i) {
        const int   row = g * 4 + i;
        const float mr  = m_f[row];
        const float th  = tsel[row];
        const float e0  = __expf(-mr);
        const float Z   = zsum[row] + (float)(NN - scnt[row]) * e0;
        const float iZ  = 1.0f / Z;
        const float b0  = e0 * iZ;
        float* po = out + (size_t)(row0 + row) * NN + wbase + cl;
        #pragma unroll
        for (int t = 0; t < TPW; ++t) {
            const float v = (i < 2) ? (float)((i == 0) ? s01[t].x : s01[t].y)
                                    : (float)((i == 2) ? s23[t].x : s23[t].y);
            po[t * 16] = (v > th) ? __expf(v - mr) * iZ : b0;
        }
    }
}

extern "C" void kernel_launch(void* const* d_in, const int* in_sizes, int n_in,
                              void* d_out, int out_size, void* d_ws, size_t ws_size,
                              hipStream_t stream) {
    const float* nv1   = (const float*)d_in[0];
    const float* nv2   = (const float*)d_in[1];
    const int*   topkp = (const int*)d_in[2];
    float*       out   = (float*)d_out;
    dim3 grid(NN / ROWS), block(NT);
    hipLaunchKernelGGL(sag_mfma, grid, block, 0, stream, nv1, nv2, topkp, out);
}

// Round 6
// 239.506 us; speedup vs baseline: 3.3850x; 3.3850x over previous
//
#include <hip/hip_runtime.h>

#define NN 8192      // rows == cols
#define DD 64        // inner dim
#define ROWS 16      // rows per block (one 16-row MFMA band)
#define NT 1024      // threads per block = 16 waves
#define NWAVE 16
#define TPW 32       // 16-col tiles per wave: 8192 / 16 waves / 16 cols
#define NCH 16       // epilogue chunks (2 tiles = 32 cols each)
#define EPIW 34      // padded epilogue row stride (floats): even (b64 align), <=2-way write conflicts
#define NBINS 128
#define LCAP 64
#define WINDOW 12.0f // values below rowmax-12 contribute < 6e-6 to any output

typedef _Float16 half8 __attribute__((ext_vector_type(8)));
typedef _Float16 half2 __attribute__((ext_vector_type(2)));
typedef float    f32x4 __attribute__((ext_vector_type(4)));
typedef float    f32x2 __attribute__((ext_vector_type(2)));

// value of (row-quad i, tile t) from packed score regs; folds statically in unrolled loops
#define SVAL(i, t) ((i) == 0 ? (float)s01[t].x : (i) == 1 ? (float)s01[t].y \
                  : (i) == 2 ? (float)s23[t].x : (float)s23[t].y)

// ---- pre-pass: nv2 [64][8192] fp32 -> B^T [8192][64] fp16 in d_ws ----
__global__ __launch_bounds__(256) void transp_f16(
    const float* __restrict__ in, _Float16* __restrict__ outT)
{
    __shared__ float t[64][65];
    const int c0 = blockIdx.x * 64;
    for (int i = threadIdx.x; i < 64 * 64; i += 256) {
        const int r = i >> 6, c = i & 63;
        t[c][r] = in[(size_t)r * NN + c0 + c];      // coalesced fp32 reads
    }
    __syncthreads();
    for (int i = threadIdx.x; i < 64 * 64; i += 256) {
        const int c = i >> 6, r = i & 63;           // consecutive tid -> consecutive r
        outT[(size_t)(c0 + c) * DD + r] = (_Float16)t[c][r];  // contiguous 2B stores
    }
}

__global__ __launch_bounds__(NT, 4) void sag_mfma(
    const float* __restrict__ nv1,
    const _Float16* __restrict__ bt,   // B^T fp16 [NN][DD]
    const int* __restrict__ topkp,
    float* __restrict__ out)
{
    __shared__ int   hist[ROWS][NBINS];
    __shared__ float blist[ROWS][LCAP];
    __shared__ int   bcount[ROWS];
    __shared__ float mpart[NWAVE][ROWS];
    __shared__ float zpart[NWAVE][ROWS];
    __shared__ int   cpart[NWAVE][ROWS];
    __shared__ float m_f[ROWS];
    __shared__ float tsel[ROWS];
    __shared__ float zsum[ROWS];
    __shared__ int   scnt[ROWS];
    __shared__ int   binb[ROWS];
    __shared__ int   needv[ROWS];
    __shared__ float epi[NWAVE][ROWS][EPIW];   // per-wave private epilogue staging

    const int tid  = threadIdx.x;
    const int wv   = tid >> 6;          // wave 0..15
    const int ln   = tid & 63;
    const int g    = ln >> 4;           // lane group 0..3 (row-quad)
    const int cl   = ln & 15;           // col-within-tile, also A-row index
    const int row0 = blockIdx.x * ROWS;
    const int K    = topkp[0];

    // ---- init LDS ----
    for (int i = tid; i < ROWS * NBINS; i += NT) (&hist[0][0])[i] = 0;
    if (tid < ROWS) bcount[tid] = 0;

    // ---- A fragments: af[ks][j] = A[row0+cl][8g+j+32ks] (fp16) ----
    half8 af[2];
    {
        const float* pa = nv1 + (size_t)(row0 + cl) * DD + g * 8;
        #pragma unroll
        for (int ks = 0; ks < 2; ++ks)
            #pragma unroll
            for (int j = 0; j < 8; ++j)
                af[ks][j] = (_Float16)pa[ks * 32 + j];
    }
    __syncthreads();

    // ---- GEMM: wave wv owns cols [wv*512, wv*512+512) ----
    // C/D layout (m89-verified): lane holds col = cl, rows g*4 + {0..3}
    // B frag: bf[j] = B[8g+j+32ks][col] = bt[col*64 + 8g+32ks+j] -> one dwordx4 per MFMA
    const int wbase = wv * (NN / NWAVE);
    const _Float16* pbt = bt + (size_t)(wbase + cl) * DD + g * 8;

    half2 s01[TPW];  // packed scores, rows g*4+0, g*4+1
    half2 s23[TPW];  // packed scores, rows g*4+2, g*4+3

    #pragma unroll
    for (int t = 0; t < TPW; ++t) {
        const _Float16* p = pbt + t * (16 * DD);
        f32x4 acc = {0.f, 0.f, 0.f, 0.f};
        const half8 b0 = *reinterpret_cast<const half8*>(p);        // rows 8g..8g+7
        const half8 b1 = *reinterpret_cast<const half8*>(p + 32);   // rows 8g+32..8g+39
        acc = __builtin_amdgcn_mfma_f32_16x16x32_f16(af[0], b0, acc, 0, 0, 0);
        acc = __builtin_amdgcn_mfma_f32_16x16x32_f16(af[1], b1, acc, 0, 0, 0);
        s01[t].x = (_Float16)fmaxf(acc[0], 0.f);
        s01[t].y = (_Float16)fmaxf(acc[1], 0.f);
        s23[t].x = (_Float16)fmaxf(acc[2], 0.f);
        s23[t].y = (_Float16)fmaxf(acc[3], 0.f);
    }

    // ---- row max over stored (fp16-rounded) values ----
    float mx[4] = {0.f, 0.f, 0.f, 0.f};
    #pragma unroll
    for (int t = 0; t < TPW; ++t) {
        mx[0] = fmaxf(mx[0], (float)s01[t].x);
        mx[1] = fmaxf(mx[1], (float)s01[t].y);
        mx[2] = fmaxf(mx[2], (float)s23[t].x);
        mx[3] = fmaxf(mx[3], (float)s23[t].y);
    }
    #pragma unroll
    for (int off = 1; off <= 8; off <<= 1) {
        #pragma unroll
        for (int i = 0; i < 4; ++i) mx[i] = fmaxf(mx[i], __shfl_xor(mx[i], off));
    }
    if (cl == 0) {
        #pragma unroll
        for (int i = 0; i < 4; ++i) mpart[wv][g * 4 + i] = mx[i];
    }
    __syncthreads();
    if (tid < ROWS) {
        float mm = 0.f;
        for (int w = 0; w < NWAVE; ++w) mm = fmaxf(mm, mpart[w][tid]);
        m_f[tid] = mm;
    }
    __syncthreads();

    // ---- histogram of in-window values ----
    const float invw = (float)NBINS / WINDOW;
    #pragma unroll
    for (int i = 0; i < 4; ++i) {
        const int   row = g * 4 + i;
        const float lbr = fmaxf(m_f[row] - WINDOW, 0.f);
        #pragma unroll
        for (int t = 0; t < TPW; ++t) {
            const float v = SVAL(i, t);
            if (v > lbr) {
                int bi = (int)((v - lbr) * invw);
                bi = bi < NBINS - 1 ? bi : NBINS - 1;
                atomicAdd(&hist[row][bi], 1);
            }
        }
    }
    __syncthreads();

    // ---- scan from top: boundary bin where cumulative reaches K ----
    if (tid < ROWS) {
        int cum = 0, b = -1, nd = 0;
        for (int i = NBINS - 1; i >= 0; --i) {
            const int h = hist[tid][i];
            if (cum + h >= K) { b = i; nd = K - cum; break; }
            cum += h;
        }
        binb[tid]  = b;
        needv[tid] = nd;
        if (b < 0) tsel[tid] = fmaxf(m_f[tid] - WINDOW, 0.f);
    }
    __syncthreads();

    // ---- collect boundary-bin values ----
    #pragma unroll
    for (int i = 0; i < 4; ++i) {
        const int row = g * 4 + i;
        const int b   = binb[row];
        if (b >= 0) {
            const float lbr = fmaxf(m_f[row] - WINDOW, 0.f);
            #pragma unroll
            for (int t = 0; t < TPW; ++t) {
                const float v = SVAL(i, t);
                if (v > lbr) {
                    int bi = (int)((v - lbr) * invw);
                    bi = bi < NBINS - 1 ? bi : NBINS - 1;
                    if (bi == b) {
                        const int p = atomicAdd(&bcount[row], 1);
                        if (p < LCAP) blist[row][p] = v;
                    }
                }
            }
        }
    }
    __syncthreads();

    // ---- exact rank within boundary bin: wave r refines row r ----
    {
        const int r = wv;   // 16 waves == 16 rows
        if (binb[r] >= 0) {
            const int n  = min(bcount[r], LCAP);
            const int nd = needv[r];
            const float v = (ln < n) ? blist[r][ln] : -1.f;
            int rank = 0;
            for (int j = 0; j < LCAP; ++j) {
                const float vj = __shfl(v, j);
                rank += (vj > v) ? 1 : 0;
            }
            float cand = (ln < n && rank < nd) ? v : 3.4e38f;
            #pragma unroll
            for (int off = 32; off; off >>= 1) cand = fminf(cand, __shfl_xor(cand, off));
            if (ln == 0) tsel[r] = __int_as_float(__float_as_int(cand) - 1);
        }
    }
    __syncthreads();

    // ---- Z reduction (deterministic order) ----
    #pragma unroll
    for (int i = 0; i < 4; ++i) {
        const int   row = g * 4 + i;
        const float mr  = m_f[row];
        const float th  = tsel[row];
        float part = 0.f;
        int   cnt  = 0;
        #pragma unroll
        for (int t = 0; t < TPW; ++t) {
            const float v = SVAL(i, t);
            const bool sel = v > th;
            const float e  = __expf(v - mr);
            part += sel ? e : 0.f;
            cnt  += sel ? 1 : 0;
        }
        #pragma unroll
        for (int off = 1; off <= 8; off <<= 1) {
            part += __shfl_xor(part, off);
            cnt  += __shfl_xor(cnt, off);
        }
        if (cl == 0) { zpart[wv][row] = part; cpart[wv][row] = cnt; }
    }
    __syncthreads();
    if (tid < ROWS) {
        float z = 0.f; int c2 = 0;
        for (int w = 0; w < NWAVE; ++w) { z += zpart[w][tid]; c2 += cpart[w][tid]; }
        zsum[tid] = z; scnt[tid] = c2;
    }
    __syncthreads();

    // ---- epilogue: per-row constants ----
    float mr4[4], th4[4], iZ4[4], b04[4];
    #pragma unroll
    for (int i = 0; i < 4; ++i) {
        const int row = g * 4 + i;
        mr4[i] = m_f[row];
        th4[i] = tsel[row];
        const float e0 = __expf(-mr4[i]);
        const float Z  = zsum[row] + (float)(NN - scnt[row]) * e0;
        iZ4[i] = 1.0f / Z;
        b04[i] = e0 * iZ4[i];
    }

    // ---- LDS-staged coalesced write-out: 32-col chunks ----
    // wave-private region, no barriers; write <=2-way bank conflict; read b64;
    // each global store instr = 4 rows x 128B full lines (no partial-line RMW)
    float* myLds = &epi[wv][0][0];
    #pragma unroll
    for (int ch = 0; ch < NCH; ++ch) {
        #pragma unroll
        for (int p = 0; p < 2; ++p) {
            const int t = ch * 2 + p;
            #pragma unroll
            for (int i = 0; i < 4; ++i) {
                const float v = SVAL(i, t);
                const float o = (v > th4[i]) ? __expf(v - mr4[i]) * iZ4[i] : b04[i];
                myLds[(g * 4 + i) * EPIW + p * 16 + cl] = o;
            }
        }
        #pragma unroll
        for (int it = 0; it < 4; ++it) {
            const int r  = (ln >> 4) + it * 4;
            const int c2 = (ln & 15) * 2;
            const f32x2 val = *reinterpret_cast<const f32x2*>(&myLds[r * EPIW + c2]);
            *reinterpret_cast<f32x2*>(&out[(size_t)(row0 + r) * NN + wbase + ch * 32 + c2]) = val;
        }
    }
}

extern "C" void kernel_launch(void* const* d_in, const int* in_sizes, int n_in,
                              void* d_out, int out_size, void* d_ws, size_t ws_size,
                              hipStream_t stream) {
    const float* nv1   = (const float*)d_in[0];
    const float* nv2   = (const float*)d_in[1];
    const int*   topkp = (const int*)d_in[2];
    float*       out   = (float*)d_out;
    _Float16*    bt    = (_Float16*)d_ws;   // NN*DD*2 = 1 MB of scratch

    hipLaunchKernelGGL(transp_f16, dim3(NN / 64), dim3(256), 0, stream, nv2, bt);
    hipLaunchKernelGGL(sag_mfma, dim3(NN / ROWS), dim3(NT), 0, stream, nv1, bt, topkp, out);
}